// Round 1
// baseline (24.632 us; speedup 1.0000x reference)
//
#include <hip/hip_runtime.h>

// TT-embedding: vocab (50,50,80), embed (8,4,4), rank 16, N=8192, fp32.
// cores:
//   core0: (1, 50, 8, 16)   -> A[i0][e0][r1]
//   core1: (16, 50, 4, 16)  -> B[r1][i1][e1][r2]
//   core2: (16, 80, 4, 1)   -> C[r2][i2][e2]
// out[n][e0*16+e1*4+e2] = sum_{r1,r2} A*B*C

#define V0 50
#define V1 50
#define V2 80
#define E0C 8
#define E1C 4
#define E2C 4
#define RR 16
#define NIDX 8192

__global__ __launch_bounds__(256) void tt_embed_kernel(
    const int* __restrict__ indices,
    const float* __restrict__ c0,
    const float* __restrict__ c1,
    const float* __restrict__ c2,
    float* __restrict__ out)
{
    const int t = blockIdx.x * 256 + threadIdx.x;
    const int n = t >> 5;          // index id (32 threads per index)
    if (n >= NIDX) return;
    const int sub = t & 31;        // (e0,e1) pair
    const int e0 = sub >> 2;       // 0..7
    const int e1 = sub & 3;        // 0..3

    const int i  = indices[n];
    const int i0 = i / (V1 * V2);
    const int rem = i - i0 * (V1 * V2);
    const int i1 = rem / V2;
    const int i2 = rem - i1 * V2;

    // ---- load A[r1] = c0[(i0*E0 + e0)*R + r1], contiguous 16 f32 (64B aligned)
    const float4* A4 = (const float4*)(c0 + ((size_t)i0 * E0C + e0) * RR);
    float a[RR];
#pragma unroll
    for (int q = 0; q < 4; ++q) {
        float4 v = A4[q];
        a[q * 4 + 0] = v.x; a[q * 4 + 1] = v.y;
        a[q * 4 + 2] = v.z; a[q * 4 + 3] = v.w;
    }

    // ---- t[r2] = sum_r1 a[r1] * B[r1][i1][e1][r2]
    float tr[RR];
#pragma unroll
    for (int r2 = 0; r2 < RR; ++r2) tr[r2] = 0.0f;

    const float* Bbase = c1 + ((size_t)i1 * E1C + e1) * RR;  // + r1*V1*E1*R
#pragma unroll
    for (int r1 = 0; r1 < RR; ++r1) {
        const float4* B4 = (const float4*)(Bbase + (size_t)r1 * (V1 * E1C * RR));
        const float ar = a[r1];
#pragma unroll
        for (int q = 0; q < 4; ++q) {
            float4 b = B4[q];
            tr[q * 4 + 0] = fmaf(ar, b.x, tr[q * 4 + 0]);
            tr[q * 4 + 1] = fmaf(ar, b.y, tr[q * 4 + 1]);
            tr[q * 4 + 2] = fmaf(ar, b.z, tr[q * 4 + 2]);
            tr[q * 4 + 3] = fmaf(ar, b.w, tr[q * 4 + 3]);
        }
    }

    // ---- out[e2] = sum_r2 t[r2] * C[r2][i2][e2]; C row for r2 is a float4 over e2
    const float4* C4 = (const float4*)(c2 + (size_t)i2 * E2C);  // + r2*V2 float4s
    float o0 = 0.f, o1 = 0.f, o2 = 0.f, o3 = 0.f;
#pragma unroll
    for (int r2 = 0; r2 < RR; ++r2) {
        float4 c = C4[(size_t)r2 * V2];
        o0 = fmaf(tr[r2], c.x, o0);
        o1 = fmaf(tr[r2], c.y, o1);
        o2 = fmaf(tr[r2], c.z, o2);
        o3 = fmaf(tr[r2], c.w, o3);
    }

    // out row: n*128 + sub*4 .. +3  (sub*4 = e0*16 + e1*4), coalesced float4
    *(float4*)(out + (size_t)n * 128 + sub * 4) = make_float4(o0, o1, o2, o3);
}

extern "C" void kernel_launch(void* const* d_in, const int* in_sizes, int n_in,
                              void* d_out, int out_size, void* d_ws, size_t ws_size,
                              hipStream_t stream) {
    const int*   indices = (const int*)d_in[0];
    const float* c0      = (const float*)d_in[1];
    const float* c1      = (const float*)d_in[2];
    const float* c2      = (const float*)d_in[3];
    float*       out     = (float*)d_out;

    const int total  = NIDX * 32;          // 32 threads per index
    const int block  = 256;
    const int grid   = (total + block - 1) / block;   // 1024
    tt_embed_kernel<<<grid, block, 0, stream>>>(indices, c0, c1, c2, out);
}

// Round 2
// 15.687 us; speedup vs baseline: 1.5703x; 1.5703x over previous
//
#include <hip/hip_runtime.h>

// TT-embedding: vocab (50,50,80), embed (8,4,4), rank 16, N=8192, fp32.
//   core0: (1, 50, 8, 16)   -> A[i0][e0][r1]
//   core1: (16, 50, 4, 16)  -> B[r1][i1][e1][r2]
//   core2: (16, 80, 4, 1)   -> C[r2][i2][e2]
// out[n][e0*16+e1*4+e2] = sum_{r1,r2} A*B*C
//
// Two-stage: k1 precomputes W12[pair][r1][e1][e2] = sum_r2 B*C for all
// pair = i1*80+i2 (4000 pairs, 3.9 MB in d_ws, coalesced float4 stores).
// k2 gathers: out = sum_r1 A[i0][e0][r1] * W12[pair][r1][e1][:] — per index
// W12 chunk is 1 KB CONTIGUOUS (vs 16 chunks of 256B spaced 12.8 KB when
// gathering core1 directly), cutting L1 line lookups ~6x.

#define V1 50
#define V2 80
#define RR 16
#define NIDX 8192
#define NPAIR (V1 * V2)          // 4000

// ---- k1: 4000 pairs x 16 r1 x 4 e1 threads, each produces float4 over e2.
// o = ((pair*16 + r1)*4 + e1); store addr = w12 + o*4 floats  (fully coalesced)
__global__ __launch_bounds__(256) void tt_k1(
    const float* __restrict__ c1,
    const float* __restrict__ c2,
    float* __restrict__ w12)
{
    const int o = blockIdx.x * 256 + threadIdx.x;   // [0, 256000)
    const int e1 = o & 3;
    const int r1 = (o >> 2) & 15;
    const int pair = o >> 6;                        // [0, 4000)
    const int i1 = pair / V2;
    const int i2 = pair - i1 * V2;

    // core1 row: 16 contiguous floats (64B aligned)
    const float4* B4 = (const float4*)(c1 + (((size_t)r1 * V1 + i1) * 4 + e1) * RR);
    float b[RR];
#pragma unroll
    for (int q = 0; q < 4; ++q) {
        float4 v = B4[q];
        b[q * 4 + 0] = v.x; b[q * 4 + 1] = v.y;
        b[q * 4 + 2] = v.z; b[q * 4 + 3] = v.w;
    }

    float o0 = 0.f, o1 = 0.f, o2 = 0.f, o3 = 0.f;
    const float4* C4 = (const float4*)(c2 + (size_t)i2 * 4);   // + r2*V2 float4s
#pragma unroll
    for (int r2 = 0; r2 < RR; ++r2) {
        float4 c = C4[(size_t)r2 * V2];
        o0 = fmaf(b[r2], c.x, o0);
        o1 = fmaf(b[r2], c.y, o1);
        o2 = fmaf(b[r2], c.z, o2);
        o3 = fmaf(b[r2], c.w, o3);
    }
    ((float4*)w12)[o] = make_float4(o0, o1, o2, o3);
}

// ---- k2: 32 threads per index; thread = (e0, e1); reads A row (16 f32) and
// W12[pair][r1][e1][:] (16 x float4, stride 64B within a contiguous 1KB chunk)
__global__ __launch_bounds__(256) void tt_k2(
    const int* __restrict__ indices,
    const float* __restrict__ c0,
    const float* __restrict__ w12,
    float* __restrict__ out)
{
    const int t = blockIdx.x * 256 + threadIdx.x;
    const int n = t >> 5;                 // index id
    const int sub = t & 31;
    const int e0 = sub >> 2;              // 0..7
    const int e1 = sub & 3;               // 0..3

    const int i  = indices[n];
    const int i0 = i / (V1 * V2);
    const int pair = i - i0 * (V1 * V2);  // i1*80 + i2

    // A[i0][e0][r1]: 16 contiguous floats
    const float4* A4 = (const float4*)(c0 + ((size_t)i0 * 8 + e0) * RR);
    float a[RR];
#pragma unroll
    for (int q = 0; q < 4; ++q) {
        float4 v = A4[q];
        a[q * 4 + 0] = v.x; a[q * 4 + 1] = v.y;
        a[q * 4 + 2] = v.z; a[q * 4 + 3] = v.w;
    }

    // W12 chunk base for this (pair, e1): float4 index = (pair*16 + r1)*4 + e1
    const float4* W4 = (const float4*)w12 + (size_t)pair * 64 + e1;
    float o0 = 0.f, o1 = 0.f, o2 = 0.f, o3 = 0.f;
#pragma unroll
    for (int r1 = 0; r1 < RR; ++r1) {
        float4 w = W4[(size_t)r1 * 4];
        o0 = fmaf(a[r1], w.x, o0);
        o1 = fmaf(a[r1], w.y, o1);
        o2 = fmaf(a[r1], w.z, o2);
        o3 = fmaf(a[r1], w.w, o3);
    }

    *(float4*)(out + (size_t)n * 128 + sub * 4) = make_float4(o0, o1, o2, o3);
}

extern "C" void kernel_launch(void* const* d_in, const int* in_sizes, int n_in,
                              void* d_out, int out_size, void* d_ws, size_t ws_size,
                              hipStream_t stream) {
    const int*   indices = (const int*)d_in[0];
    const float* c0      = (const float*)d_in[1];
    const float* c1      = (const float*)d_in[2];
    const float* c2      = (const float*)d_in[3];
    float*       out     = (float*)d_out;
    float*       w12     = (float*)d_ws;   // 4000*256*4B = 4.096 MB

    // k1: 4000 pairs * 64 threads each = 256000 threads -> 1000 blocks
    tt_k1<<<1000, 256, 0, stream>>>(c1, c2, w12);
    // k2: 8192 indices * 32 threads = 262144 threads -> 1024 blocks
    tt_k2<<<1024, 256, 0, stream>>>(indices, c0, w12, out);
}

// Round 3
// 12.981 us; speedup vs baseline: 1.8976x; 1.2084x over previous
//
#include <hip/hip_runtime.h>

// TT-embedding: vocab (50,50,80), embed (8,4,4), rank 16, N=8192, fp32.
//   core0: (1, 50, 8, 16)   -> A[i0][e0][r1]
//   core1: (16, 50, 4, 16)  -> B[r1][i1][e1][r2]
//   core2: (16, 80, 4, 1)   -> C[r2][i2][e2]
// out[n][e0*16+e1*4+e2] = sum_{r1,r2} A*B*C
//
// Single fused kernel (round 2's two-dispatch W12 split paid a kernel
// boundary + global round-trip). Per block: 8 indices.
//   Phase A: 512 tasks (idx,r1,e1) -> T[idx][r1][e1][e2] = sum_r2 B*C,
//            2 tasks/thread, result staged in 8 KB LDS.
//   Phase B: thread (idx,e0,e1): out = sum_r1 A[i0,e0,r1] * T[idx][r1][e1][:]
// Same contraction association as the reference einsum ((B*C) then A) -> same
// rounding as round 2 (absmax 1.2e-7).

#define V1 50
#define V2 80
#define RR 16
#define NIDX 8192
#define IDX_PER_BLOCK 8

__global__ __launch_bounds__(256) void tt_fused(
    const int* __restrict__ indices,
    const float* __restrict__ c0,
    const float* __restrict__ c1,
    const float* __restrict__ c2,
    float* __restrict__ out)
{
    __shared__ float4 T[IDX_PER_BLOCK * 64];   // [idx][r1][e1] -> float4 over e2 (8 KB)

    const int t = threadIdx.x;
    const int nbase = blockIdx.x * IDX_PER_BLOCK;

    // ---------- Phase A: T[idx][r1][e1][:] = sum_r2 B[r1,i1,e1,r2] * C[r2,i2,:]
#pragma unroll
    for (int s = 0; s < 2; ++s) {
        const int task = t + s * 256;           // [0, 512)
        const int e1  = task & 3;
        const int r1  = (task >> 2) & 15;
        const int idx = task >> 6;              // [0, 8)

        const int i    = indices[nbase + idx];
        const int i0   = i / (V1 * V2);
        const int pair = i - i0 * (V1 * V2);
        const int i1   = pair / V2;
        const int i2   = pair - i1 * V2;

        // B row: 16 contiguous floats (64B); consecutive e1 -> contiguous 256B
        const float4* B4 = (const float4*)(c1 + (((size_t)r1 * V1 + i1) * 4 + e1) * RR);
        float b[RR];
#pragma unroll
        for (int q = 0; q < 4; ++q) {
            float4 v = B4[q];
            b[q * 4 + 0] = v.x; b[q * 4 + 1] = v.y;
            b[q * 4 + 2] = v.z; b[q * 4 + 3] = v.w;
        }

        // C[r2][i2][:] : float4 at stride 320 floats (c2 = 20KB, L1-resident)
        const float4* C4 = (const float4*)(c2 + (size_t)i2 * 4);
        float o0 = 0.f, o1 = 0.f, o2 = 0.f, o3 = 0.f;
#pragma unroll
        for (int r2 = 0; r2 < RR; ++r2) {
            float4 c = C4[(size_t)r2 * V2];
            o0 = fmaf(b[r2], c.x, o0);
            o1 = fmaf(b[r2], c.y, o1);
            o2 = fmaf(b[r2], c.z, o2);
            o3 = fmaf(b[r2], c.w, o3);
        }
        T[task] = make_float4(o0, o1, o2, o3);  // consecutive threads -> consecutive float4
    }

    __syncthreads();

    // ---------- Phase B: thread u = (idx, e0, e1)
    const int e1  = t & 3;
    const int e0  = (t >> 2) & 7;
    const int idx = t >> 5;                     // [0, 8)
    const int n   = nbase + idx;

    const int i  = indices[n];
    const int i0 = i / (V1 * V2);

    // A[i0][e0][:] : 16 contiguous floats
    const float4* A4 = (const float4*)(c0 + ((size_t)i0 * 8 + e0) * RR);
    float a[RR];
#pragma unroll
    for (int q = 0; q < 4; ++q) {
        float4 v = A4[q];
        a[q * 4 + 0] = v.x; a[q * 4 + 1] = v.y;
        a[q * 4 + 2] = v.z; a[q * 4 + 3] = v.w;
    }

    const float4* Tb = &T[idx * 64 + e1];       // + r1*4
    float o0 = 0.f, o1 = 0.f, o2 = 0.f, o3 = 0.f;
#pragma unroll
    for (int r1 = 0; r1 < RR; ++r1) {
        float4 w = Tb[r1 * 4];
        o0 = fmaf(a[r1], w.x, o0);
        o1 = fmaf(a[r1], w.y, o1);
        o2 = fmaf(a[r1], w.z, o2);
        o3 = fmaf(a[r1], w.w, o3);
    }

    // out offset: n*128 + (e0*16 + e1*4), coalesced float4 per wave
    *(float4*)(out + (size_t)n * 128 + (e0 * 4 + e1) * 4) = make_float4(o0, o1, o2, o3);
}

extern "C" void kernel_launch(void* const* d_in, const int* in_sizes, int n_in,
                              void* d_out, int out_size, void* d_ws, size_t ws_size,
                              hipStream_t stream) {
    const int*   indices = (const int*)d_in[0];
    const float* c0      = (const float*)d_in[1];
    const float* c1      = (const float*)d_in[2];
    const float* c2      = (const float*)d_in[3];
    float*       out     = (float*)d_out;

    const int grid = NIDX / IDX_PER_BLOCK;   // 1024 blocks
    tt_fused<<<grid, 256, 0, stream>>>(indices, c0, c1, c2, out);
}